// Round 9
// baseline (259.820 us; speedup 1.0000x reference)
//
#include <hip/hip_runtime.h>

typedef _Float16 half8 __attribute__((ext_vector_type(8)));
typedef float floatx4 __attribute__((ext_vector_type(4)));
typedef float f32x4 __attribute__((ext_vector_type(4)));
typedef unsigned int uint4v __attribute__((ext_vector_type(4)));

#define B_DIM 8
#define C_DIM 64
#define T_DIM 128
#define N_DIM 207
#define O_DIM 64
#define CSTR  (T_DIM * N_DIM)     // 26496 = 207 * 128 (exact: flat-tn tiles fit)
#define LOG2E 1.44269504f

// ---------------------------------------------------------------------------
// Kernel 0: pack Wq|Wk|Wv (fp32 [64 o][64 c]) -> fp16 in d_ws. [arr][o][c].
// ---------------------------------------------------------------------------
__global__ void pack_w(const float* __restrict__ Wq,
                       const float* __restrict__ Wk,
                       const float* __restrict__ Wv,
                       _Float16* __restrict__ ws)
{
    int i = threadIdx.x + blockIdx.x * blockDim.x;
    const int per = O_DIM * C_DIM;          // 4096
    for (int m = i; m < 3 * per; m += blockDim.x * gridDim.x) {
        int arr = m / per, rem = m % per;
        const float* W = (arr == 0) ? Wq : (arr == 1) ? Wk : Wv;
        ws[m] = (_Float16)W[rem];
    }
}

#define GLDS4(gp_, lp_)                                                      \
    __builtin_amdgcn_global_load_lds(                                        \
        (const __attribute__((address_space(1))) void*)(gp_),                \
        (__attribute__((address_space(3))) void*)(lp_), 4, 0, 0)

#define MFMA16(a_, b_, c_) __builtin_amdgcn_mfma_f32_16x16x32_f16(a_, b_, c_, 0, 0, 0)
#define PKU(a_, b_) __builtin_bit_cast(unsigned int, __builtin_amdgcn_cvt_pkrtz((a_), (b_)))

// ---------------------------------------------------------------------------
// Kernel A: projection GEMM. Out[arr][b][o][tn] (f16) = W[o,:]X[:,tn] + bias.
// Grid (207 tn-tiles, 24 arr*b); block 256 = 4 waves; tile 64o x 128tn.
// LDS X-tile [64 c][128 tn] rows padded to 129 words -> frag reads 2-way
// bank aliased (free, m136). Staging: 32 contiguous GLDS4/wave, ONE barrier
// per block. All addresses verified in-bounds (max = last element exactly).
// ---------------------------------------------------------------------------
__global__ __launch_bounds__(256, 4)
void proj_gemm(const float* __restrict__ q,
               const float* __restrict__ k,
               const float* __restrict__ v,
               const float* __restrict__ bq,
               const float* __restrict__ bk,
               const float* __restrict__ bv,
               const _Float16* __restrict__ wpk,
               _Float16* __restrict__ proj)
{
    __shared__ __align__(16) float xt[64 * 129 + 4];   // padded rows, 33 KB

    const int tid = threadIdx.x, lane = tid & 63, wv = tid >> 6;
    const int nq = lane & 15, qd = lane >> 4;
    const int tile = blockIdx.x;          // 0..206
    const int ab   = blockIdx.y;          // arr*8 + b
    const int arr  = ab >> 3, b = ab & 7;

    const float* X    = ((arr == 0) ? q : (arr == 1) ? k : v) + (size_t)b * C_DIM * CSTR;
    const float* bias = (arr == 0) ? bq : (arr == 1) ? bk : bv;
    const int tn0 = tile * 128;

    // ---- stage: wave wv owns c rows [wv*16, wv*16+16), 2 half-rows each ----
    {
        const float* s0 = X + tn0 + lane;
        #pragma unroll
        for (int i = 0; i < 16; ++i) {
            const int c = wv * 16 + i;
            GLDS4(s0 + (size_t)c * CSTR,      &xt[c * 129]);
            GLDS4(s0 + (size_t)c * CSTR + 64, &xt[c * 129 + 64]);
        }
    }
    __syncthreads();   // single drain per block

    // ---- A-frags (W) + bias: o-slice = wv*16 ----
    const _Float16* wrow = wpk + ((size_t)(arr * 64 + wv * 16 + nq)) * 64 + qd * 8;
    half8 af0 = *(const half8*)(wrow);
    half8 af1 = *(const half8*)(wrow + 32);
    float br[4];
    #pragma unroll
    for (int j = 0; j < 4; ++j) br[j] = bias[wv * 16 + qd * 4 + j];

    floatx4 acc[8];
    #pragma unroll
    for (int f = 0; f < 8; ++f) acc[f] = (floatx4){0.f, 0.f, 0.f, 0.f};

    // B-frag: X[c = qd*8 + kk*32 + jj][tn0 + f*16 + nq]
    const float* lb = &xt[qd * 8 * 129 + nq];
    #pragma unroll
    for (int f = 0; f < 8; ++f) {
        #pragma unroll
        for (int kk = 0; kk < 2; ++kk) {
            const float* p = lb + kk * (32 * 129) + f * 16;
            uint4v t_;
            t_[0] = PKU(p[0 * 129], p[1 * 129]);
            t_[1] = PKU(p[2 * 129], p[3 * 129]);
            t_[2] = PKU(p[4 * 129], p[5 * 129]);
            t_[3] = PKU(p[6 * 129], p[7 * 129]);
            half8 fb = __builtin_bit_cast(half8, t_);
            acc[f] = MFMA16((kk == 0) ? af0 : af1, fb, acc[f]);
        }
    }

    // ---- store f16: o = wv*16 + qd*4 + j, col tn0 + f*16 + nq ----
    #pragma unroll
    for (int j = 0; j < 4; ++j) {
        _Float16* rp = proj + ((size_t)(ab * 64 + wv * 16 + qd * 4 + j)) * CSTR
                            + tn0 + nq;
        #pragma unroll
        for (int f = 0; f < 8; ++f)
            rp[f * 16] = (_Float16)(acc[f][j] + br[j]);
    }
}

// ---------------------------------------------------------------------------
// Kernel B: windowed softmax over materialized Q',K',V'. Pure streaming:
// one wave owns (b, o, n-chunk 128, t-chunk 16); rolling 7-window in regs;
// no LDS, no barriers, no MFMA. exp2 via raw v_exp_f32 builtin.
// Grid (128 = og*8+tc, 2 nc, 8 b) = 2048 blocks, 8 waves/SIMD.
// All loads use per-lane CLAMPED offsets (off0/off1 <= N_DIM-1) -> provably
// in-bounds; out-of-range lanes contribute zeros via valid flags.
// ---------------------------------------------------------------------------
__global__ __launch_bounds__(256, 4)
void attn_win(const _Float16* __restrict__ proj, float* __restrict__ out)
{
    const int tid = threadIdx.x, lane = tid & 63, wv = tid >> 6;
    const int og = blockIdx.x >> 3;       // 0..15
    const int tc = blockIdx.x & 7;        // 0..7
    const int nc = blockIdx.y;            // 0..1
    const int b  = blockIdx.z;            // 0..7
    const int o  = og * 4 + wv;
    const int ta = tc * 16;
    const int nn = nc * 128 + lane * 2;
    const bool v0 = nn < N_DIM, v1 = nn + 1 < N_DIM;
    const int off0 = min(nn,     N_DIM - 1);   // clamped load offsets
    const int off1 = min(nn + 1, N_DIM - 1);

    const _Float16* Qp = proj + ((size_t)(b * 64 + o)) * CSTR;
    const _Float16* Kp = Qp + (size_t)8  * 64 * CSTR;   // arr 1
    const _Float16* Vp = Qp + (size_t)16 * 64 * CSTR;   // arr 2
    float* Op = out + ((size_t)(b * 64 + o)) * CSTR + nn;

#define LD2(base_, trow_, va_, a_, c_)                                       \
    {                                                                        \
        const _Float16* rp_ = (base_) + (size_t)(trow_) * N_DIM;             \
        float x0_ = (float)rp_[off0];                                        \
        float x1_ = (float)rp_[off1];                                        \
        a_ = (va_) ? x0_ : 0.f;                                              \
        c_ = (va_) ? x1_ : 0.f;                                              \
    }

    float k0[7], k1[7], w0[7], w1[7];
    #pragma unroll
    for (int i = 0; i < 6; ++i) {   // prefill t' = ta-3 .. ta+2 -> slots 0..5
        const int tp  = ta - 3 + i;
        const int tcl = min(max(tp, 0), T_DIM - 1);
        const bool va = (tp >= 0) && (tp < T_DIM);
        LD2(Kp, tcl, va, k0[i], k1[i]);
        LD2(Vp, tcl, va, w0[i], w1[i]);
    }

    for (int i = 0; i < 16; ++i) {
        const int t = ta + i;
        {   // newest row t+3 -> slot 6
            const int tp  = t + 3;
            const int tcl = min(tp, T_DIM - 1);
            const bool va = tp < T_DIM;
            LD2(Kp, tcl, va, k0[6], k1[6]);
            LD2(Vp, tcl, va, w0[6], w1[6]);
        }
        float q0, q1;
        LD2(Qp, t, true, q0, q1);
        q0 *= LOG2E; q1 *= LOG2E;

        float num0 = 0.f, den0 = 0.f, num1 = 0.f, den1 = 0.f;
        {
            float s[7];
            #pragma unroll
            for (int u = 0; u < 7; ++u) s[u] = q0 * k0[u];
            float mx = s[0];
            #pragma unroll
            for (int u = 1; u < 7; ++u) mx = fmaxf(mx, s[u]);
            #pragma unroll
            for (int u = 0; u < 7; ++u) {
                const float e = __builtin_amdgcn_exp2f(s[u] - mx);
                den0 += e; num0 = fmaf(e, w0[u], num0);
            }
        }
        {
            float s[7];
            #pragma unroll
            for (int u = 0; u < 7; ++u) s[u] = q1 * k1[u];
            float mx = s[0];
            #pragma unroll
            for (int u = 1; u < 7; ++u) mx = fmaxf(mx, s[u]);
            #pragma unroll
            for (int u = 0; u < 7; ++u) {
                const float e = __builtin_amdgcn_exp2f(s[u] - mx);
                den1 += e; num1 = fmaf(e, w1[u], num1);
            }
        }
        if (v0) Op[(size_t)t * N_DIM]     = num0 * __builtin_amdgcn_rcpf(den0);
        if (v1) Op[(size_t)t * N_DIM + 1] = num1 * __builtin_amdgcn_rcpf(den1);

        #pragma unroll
        for (int u = 0; u < 6; ++u) {
            k0[u] = k0[u + 1]; k1[u] = k1[u + 1];
            w0[u] = w0[u + 1]; w1[u] = w1[u + 1];
        }
    }
#undef LD2
}

// ---------------------------------------------------------------------------
// FALLBACK: round-4-verified fused kernel (113.7 us), used if ws too small.
// ---------------------------------------------------------------------------
#define VMWAIT(N_) asm volatile("s_waitcnt vmcnt(" #N_ ")" ::: "memory")

#define FSTAGE(tg_, P_)                                                      \
    {                                                                        \
        const int tcl_  = min(max((tg_), 0), T_DIM - 1);                     \
        const int toff_ = tcl_ * N_DIM;                                      \
        _Pragma("unroll")                                                    \
        for (int arr_ = 0; arr_ < 3; ++arr_) {                               \
            const float* ab_ = (arr_ == 0) ? qb2 : (arr_ == 1) ? kb2 : vb2;  \
            _Pragma("unroll")                                                \
            for (int i_ = 0; i_ < 4; ++i_) {                                 \
                GLDS4(ab_ + toff_ + col_off[i_],                             \
                      &xls[P_][arr_][wv * 4 + i_][0][0]);                    \
            }                                                                \
        }                                                                    \
    }

#define FMKFRAG(P_, arr_, kk_, dst_)                                         \
    {                                                                        \
        const float* ch_ = &xls[P_][arr_][qd * 2 + (kk_) * 8][nq][0];        \
        f32x4 A_ = *(const f32x4*)(ch_);                                     \
        f32x4 B_ = *(const f32x4*)(ch_ + 64);                                \
        uint4v t_;                                                           \
        t_[0] = PKU(A_[0], A_[1]);  t_[1] = PKU(A_[2], A_[3]);               \
        t_[2] = PKU(B_[0], B_[1]);  t_[3] = PKU(B_[2], B_[3]);               \
        dst_ = __builtin_bit_cast(half8, t_);                                \
    }

#define FSTEP(r_, N_)                                                        \
    {                                                                        \
        __builtin_amdgcn_sched_barrier(0);                                   \
        VMWAIT(N_);                                                          \
        __builtin_amdgcn_s_barrier();                                        \
        __builtin_amdgcn_sched_barrier(0);                                   \
        if ((r_) <= 19) FSTAGE(t0 - 1 + (r_), ((r_) + 2) % 3)                \
        __builtin_amdgcn_sched_barrier(0);                                   \
        half8 fk0, fk1, fv0, fv1;                                            \
        FMKFRAG((r_) % 3, 1, 0, fk0)  FMKFRAG((r_) % 3, 1, 1, fk1)           \
        FMKFRAG((r_) % 3, 2, 0, fv0)  FMKFRAG((r_) % 3, 2, 1, fv1)           \
        floatx4 aq = {0.f, 0.f, 0.f, 0.f};                                   \
        floatx4 ak = {0.f, 0.f, 0.f, 0.f};                                   \
        floatx4 av = {0.f, 0.f, 0.f, 0.f};                                   \
        ak = MFMA16(af[1][0], fk0, ak);  ak = MFMA16(af[1][1], fk1, ak);     \
        av = MFMA16(af[2][0], fv0, av);  av = MFMA16(af[2][1], fv1, av);     \
        if ((r_) >= 3 && (r_) <= 18) {                                       \
            half8 fq0, fq1;                                                  \
            FMKFRAG((r_) % 3, 0, 0, fq0)  FMKFRAG((r_) % 3, 0, 1, fq1)       \
            aq = MFMA16(af[0][0], fq0, aq);  aq = MFMA16(af[0][1], fq1, aq); \
        }                                                                    \
        const int  tg_   = t0 - 3 + (r_);                                    \
        const bool rowv_ = (tg_ >= 0) && (tg_ < T_DIM);                      \
        _Pragma("unroll")                                                    \
        for (int j = 0; j < 4; ++j) {                                        \
            Kw[j][(r_) % 7]  = rowv_ ? (ak[j] + bk_r[j]) : 0.f;              \
            Vw[j][(r_) % 7]  = rowv_ ? (av[j] + bv_r[j]) : 0.f;              \
            Qd4[j][(r_) % 4] = aq[j] + bq_r[j];                              \
        }                                                                    \
        if ((r_) >= 6) {                                                     \
            const int to_ = t0 + (r_) - 6;                                   \
            const int n_g = n0 + nq;                                         \
            if (n_g < N_DIM) {                                               \
                _Pragma("unroll")                                            \
                for (int j = 0; j < 4; ++j) {                                \
                    const float qv = Qd4[j][((r_) + 1) % 4] * LOG2E;         \
                    float s[7];                                              \
                    _Pragma("unroll")                                        \
                    for (int i = 0; i < 7; ++i)                              \
                        s[i] = qv * Kw[j][((r_) + 1 + i) % 7];               \
                    float mx = s[0];                                         \
                    _Pragma("unroll")                                        \
                    for (int i = 1; i < 7; ++i) mx = fmaxf(mx, s[i]);        \
                    float den = 0.f, num = 0.f;                              \
                    _Pragma("unroll")                                        \
                    for (int i = 0; i < 7; ++i) {                            \
                        float e = exp2f(s[i] - mx);                          \
                        den += e;                                            \
                        num = fmaf(e, Vw[j][((r_) + 1 + i) % 7], num);       \
                    }                                                        \
                    out[((size_t)(b * O_DIM + o0 + qd * 4 + j) * T_DIM + to_) * N_DIM + n_g] \
                        = num * __builtin_amdgcn_rcpf(den);                  \
                }                                                            \
            }                                                                \
        }                                                                    \
    }

__global__ __launch_bounds__(256, 3)
void attn_mfma(const float* __restrict__ q,
               const float* __restrict__ k,
               const float* __restrict__ v,
               const float* __restrict__ bq,
               const float* __restrict__ bk,
               const float* __restrict__ bv,
               const _Float16* __restrict__ wpk,
               float* __restrict__ out)
{
    __shared__ __align__(16) float xls[3][3][16][16][4];

    const int tid  = threadIdx.x;
    const int lane = tid & 63;
    const int wv   = tid >> 6;
    const int nq   = lane & 15;
    const int qd   = lane >> 4;

    const int bid = (int)blockIdx.x + 13 * ((int)blockIdx.y + 8 * (int)blockIdx.z);
    const int swz = (bid & 7) * 104 + (bid >> 3);
    const int nb  = swz % 13;
    const int tc  = (swz / 13) & 7;
    const int b   = swz / 104;

    const int t0 = tc * 16;
    const int o0 = wv * 16;
    const int n0 = nb * 16;

    const int cl   = lane & 3;
    const int nrow = lane >> 2;
    const int n_cl = min(n0 + nrow, N_DIM - 1);
    int col_off[4];
    #pragma unroll
    for (int i = 0; i < 4; ++i)
        col_off[i] = ((wv * 4 + i) * 4 + cl) * CSTR + n_cl;

    const float* qb2 = q + (size_t)b * C_DIM * CSTR;
    const float* kb2 = k + (size_t)b * C_DIM * CSTR;
    const float* vb2 = v + (size_t)b * C_DIM * CSTR;

    half8 af[3][2];
    #pragma unroll
    for (int arr = 0; arr < 3; ++arr)
        #pragma unroll
        for (int kk = 0; kk < 2; ++kk)
            af[arr][kk] = *(const half8*)(wpk + ((size_t)(arr * 64 + o0 + nq) * 64
                                                 + qd * 8 + kk * 32));

    float bq_r[4], bk_r[4], bv_r[4];
    #pragma unroll
    for (int j = 0; j < 4; ++j) {
        const int og = o0 + qd * 4 + j;
        bq_r[j] = bq[og]; bk_r[j] = bk[og]; bv_r[j] = bv[og];
    }

    float Kw[4][7], Vw[4][7], Qd4[4][4];
    #pragma unroll
    for (int j = 0; j < 4; ++j) {
        #pragma unroll
        for (int i = 0; i < 7; ++i) { Kw[j][i] = 0.f; Vw[j][i] = 0.f; }
        #pragma unroll
        for (int i = 0; i < 4; ++i) Qd4[j][i] = 0.f;
    }

    FSTAGE(t0 - 3, 0)
    FSTAGE(t0 - 2, 1)

    FSTEP( 0, 12)  FSTEP( 1, 12)  FSTEP( 2, 12)  FSTEP( 3, 12)
    FSTEP( 4, 12)  FSTEP( 5, 12)  FSTEP( 6, 12)  FSTEP( 7, 16)
    FSTEP( 8, 20)  FSTEP( 9, 20)  FSTEP(10, 20)  FSTEP(11, 20)
    FSTEP(12, 20)  FSTEP(13, 20)  FSTEP(14, 20)  FSTEP(15, 20)
    FSTEP(16, 20)  FSTEP(17, 20)  FSTEP(18, 20)  FSTEP(19, 20)
    FSTEP(20, 20)  FSTEP(21,  8)
}

extern "C" void kernel_launch(void* const* d_in, const int* in_sizes, int n_in,
                              void* d_out, int out_size, void* d_ws, size_t ws_size,
                              hipStream_t stream)
{
    const float* q  = (const float*)d_in[0];
    const float* k  = (const float*)d_in[1];
    const float* v  = (const float*)d_in[2];
    const float* Wq = (const float*)d_in[3];
    const float* bq = (const float*)d_in[4];
    const float* Wk = (const float*)d_in[5];
    const float* bk = (const float*)d_in[6];
    const float* Wv = (const float*)d_in[7];
    const float* bv = (const float*)d_in[8];
    float* o = (float*)d_out;

    _Float16* ws_h = (_Float16*)d_ws;     // packed W: 24 KB
    hipLaunchKernelGGL(pack_w, dim3(3), dim3(256), 0, stream, Wq, Wk, Wv, ws_h);

    const size_t PROJ_OFF = 32768;
    const size_t NEED = PROJ_OFF + (size_t)3 * B_DIM * O_DIM * CSTR * sizeof(_Float16);

    if (ws_size >= NEED) {
        _Float16* proj = (_Float16*)((char*)d_ws + PROJ_OFF);
        hipLaunchKernelGGL(proj_gemm, dim3(207, 24), dim3(256), 0, stream,
                           q, k, v, bq, bk, bv, (const _Float16*)ws_h, proj);
        hipLaunchKernelGGL(attn_win, dim3(128, 2, B_DIM), dim3(256), 0, stream,
                           (const _Float16*)proj, o);
    } else {
        // fallback: round-4-verified fused kernel
        dim3 grid(13, 8, B_DIM);
        hipLaunchKernelGGL(attn_mfma, grid, dim3(256), 0, stream,
                           q, k, v, bq, bk, bv, (const _Float16*)ws_h, o);
    }
}